// Round 1
// baseline (999.896 us; speedup 1.0000x reference)
//
#include <hip/hip_runtime.h>
#include <cstddef>

#define TS 64
#define KT 16

// ---------------------------------------------------------------------------
// Generic 64x64-tile fp32 GEMM:  C[m,n] = sum_e A[m,e]*W[e,n] + bias[n]
// MODE 0: W is [K, N] row-major (W_o case)
// MODE 1: W is [H, K, 64] stacked per-head ([H,E,D]); col n -> h=n>>6, d=n&63.
//         A 64-wide col tile (n0 64-aligned) lies entirely in one head, so the
//         weight tile is contiguous [16 x 64] row-major -> coalesced float4.
// bias is flat length-N in both modes (b_q[H,D] flattens to h*64+d == n).
// ---------------------------------------------------------------------------
template<int MODE>
__global__ __launch_bounds__(256) void gemm64(
    const float* __restrict__ A, const float* __restrict__ W,
    const float* __restrict__ bias, float* __restrict__ C,
    int M, int K, int N)
{
  __shared__ float As[KT][TS + 1];   // [e][m], +1 pad: compute reads conflict-free
  __shared__ float Bs[KT][TS];       // [e][n]
  const int tid = threadIdx.x;
  const int tx = tid & 15, ty = tid >> 4;
  const int m0 = blockIdx.y * TS;
  const int n0 = blockIdx.x * TS;
  float acc[4][4] = {};
  const int lrow = tid >> 2;          // 0..63 : A row within tile
  const int lc4  = (tid & 3) * 4;     // 0..12 : e offset (float4)
  const int wrow = tid >> 4;          // 0..15 : e within k-tile
  const int wc4  = (tid & 15) * 4;    // 0..60 : n offset (float4)

  for (int kt = 0; kt < K; kt += KT) {
    // hoist global loads above the sync for latency hiding
    float4 av = *(const float4*)&A[(size_t)(m0 + lrow) * K + kt + lc4];
    float4 wv;
    if (MODE == 0) {
      wv = *(const float4*)&W[(size_t)(kt + wrow) * N + n0 + wc4];
    } else {
      wv = *(const float4*)&W[((size_t)(n0 >> 6) * K + kt + wrow) * 64 + wc4];
    }
    __syncthreads();   // previous iteration's LDS reads complete
    As[lc4 + 0][lrow] = av.x;
    As[lc4 + 1][lrow] = av.y;
    As[lc4 + 2][lrow] = av.z;
    As[lc4 + 3][lrow] = av.w;
    *(float4*)&Bs[wrow][wc4] = wv;
    __syncthreads();
    #pragma unroll
    for (int kk = 0; kk < KT; ++kk) {
      float a[4], b[4];
      #pragma unroll
      for (int i = 0; i < 4; ++i) a[i] = As[kk][ty * 4 + i];
      #pragma unroll
      for (int j = 0; j < 4; ++j) b[j] = Bs[kk][tx * 4 + j];
      #pragma unroll
      for (int i = 0; i < 4; ++i)
        #pragma unroll
        for (int j = 0; j < 4; ++j)
          acc[i][j] += a[i] * b[j];
    }
  }
  #pragma unroll
  for (int i = 0; i < 4; ++i) {
    const int m = m0 + ty * 4 + i;
    const int n = n0 + tx * 4;
    float4 o;
    o.x = acc[i][0] + bias[n + 0];
    o.y = acc[i][1] + bias[n + 1];
    o.z = acc[i][2] + bias[n + 2];
    o.w = acc[i][3] + bias[n + 3];
    *(float4*)&C[(size_t)m * N + n] = o;
  }
}

// ---------------------------------------------------------------------------
// Pass A: column softmax denominators.
// L[bh, k] = sum_q exp( (Q[bh,q,:] . K[bh,k,:]) / 32 )
// Scores ~N(0, 0.25): no max-subtraction needed (no overflow possible).
// Block: one 64-wide k-tile of one (b,h); loops over all q-tiles.
// Q/K stored as [B*S, E] rows; head h occupies cols h*64..h*64+63.
// ---------------------------------------------------------------------------
__global__ __launch_bounds__(256) void col_stats(
    const float* __restrict__ Qb, const float* __restrict__ Kb,
    float* __restrict__ L)
{
  const int S = 1024, E = 1024;
  const float scale = 0.03125f;     // 1/sqrt(1024)
  __shared__ float Ks[64][65];      // [k][d]
  __shared__ float Qs[64][65];      // [q][d]
  __shared__ float red[16][65];
  const int bh = blockIdx.y;
  const int b = bh >> 4, h = bh & 15;
  const int k0 = blockIdx.x * 64;
  const int tid = threadIdx.x;
  const int tx = tid & 15, ty = tid >> 4;
  const int r0 = tid >> 4, c4 = (tid & 15) * 4;
  const size_t rowBase = (size_t)b * S;
  const int col = h * 64 + c4;

  #pragma unroll
  for (int i = 0; i < 4; ++i) {
    const int r = r0 + 16 * i;
    float4 v = *(const float4*)&Kb[(rowBase + k0 + r) * E + col];
    Ks[r][c4 + 0] = v.x; Ks[r][c4 + 1] = v.y; Ks[r][c4 + 2] = v.z; Ks[r][c4 + 3] = v.w;
  }

  float accL[4] = {0.f, 0.f, 0.f, 0.f};   // partial column sums, k = ty*4+i
  for (int q0 = 0; q0 < S; q0 += 64) {
    __syncthreads();   // also orders the Ks/previous Qs reads
    #pragma unroll
    for (int i = 0; i < 4; ++i) {
      const int r = r0 + 16 * i;
      float4 v = *(const float4*)&Qb[(rowBase + q0 + r) * E + col];
      Qs[r][c4 + 0] = v.x; Qs[r][c4 + 1] = v.y; Qs[r][c4 + 2] = v.z; Qs[r][c4 + 3] = v.w;
    }
    __syncthreads();
    // s[k=ty*4+i][q=tx*4+j]
    float s[4][4] = {};
    for (int d = 0; d < 64; ++d) {
      float a[4], bb[4];
      #pragma unroll
      for (int i = 0; i < 4; ++i) a[i] = Ks[ty * 4 + i][d];
      #pragma unroll
      for (int j = 0; j < 4; ++j) bb[j] = Qs[tx * 4 + j][d];
      #pragma unroll
      for (int i = 0; i < 4; ++i)
        #pragma unroll
        for (int j = 0; j < 4; ++j)
          s[i][j] += a[i] * bb[j];
    }
    #pragma unroll
    for (int i = 0; i < 4; ++i) {
      float e = 0.f;
      #pragma unroll
      for (int j = 0; j < 4; ++j) e += __expf(s[i][j] * scale);
      accL[i] += e;
    }
  }
  __syncthreads();
  #pragma unroll
  for (int i = 0; i < 4; ++i) red[tx][ty * 4 + i] = accL[i];
  __syncthreads();
  if (tid < 64) {
    float l = 0.f;
    #pragma unroll
    for (int r = 0; r < 16; ++r) l += red[r][tid];
    L[(size_t)bh * S + k0 + tid] = l;
  }
}

// ---------------------------------------------------------------------------
// Pass B: out[bh,q,d] = sum_k exp(s[q,k]/32)/L[k] * V[k,d], with V = Q.
// Block: one 64-row q-tile of one (b,h); streams over k-tiles.
// Writes concat layout O[(b*S+q)*E + h*64 + d].
// ---------------------------------------------------------------------------
__global__ __launch_bounds__(256) void attn_out(
    const float* __restrict__ Qb, const float* __restrict__ Kb,
    const float* __restrict__ L, float* __restrict__ O)
{
  const int S = 1024, E = 1024;
  const float scale = 0.03125f;
  __shared__ float Qq[64][65];   // [q][d], resident
  __shared__ float Kt[64][65];   // [k][d]
  __shared__ float Vt[64][65];   // [k][d]  (= Q rows of the k range)
  __shared__ float Wl[64][65];   // [q][k]  weight tile staging
  __shared__ float Ls[64];
  const int bh = blockIdx.y;
  const int b = bh >> 4, h = bh & 15;
  const int q0 = blockIdx.x * 64;
  const int tid = threadIdx.x;
  const int tx = tid & 15, ty = tid >> 4;
  const int r0 = tid >> 4, c4 = (tid & 15) * 4;
  const size_t rowBase = (size_t)b * S;
  const int col = h * 64 + c4;

  #pragma unroll
  for (int i = 0; i < 4; ++i) {
    const int r = r0 + 16 * i;
    float4 v = *(const float4*)&Qb[(rowBase + q0 + r) * E + col];
    Qq[r][c4 + 0] = v.x; Qq[r][c4 + 1] = v.y; Qq[r][c4 + 2] = v.z; Qq[r][c4 + 3] = v.w;
  }

  float oacc[4][4] = {};   // [q=ty*4+i][d=tx*4+j]
  for (int k0 = 0; k0 < S; k0 += 64) {
    __syncthreads();   // prior GEMM2 reads of Kt/Vt/Ls done; Qq load ordered
    #pragma unroll
    for (int i = 0; i < 4; ++i) {
      const int r = r0 + 16 * i;
      float4 v = *(const float4*)&Kb[(rowBase + k0 + r) * E + col];
      Kt[r][c4 + 0] = v.x; Kt[r][c4 + 1] = v.y; Kt[r][c4 + 2] = v.z; Kt[r][c4 + 3] = v.w;
      float4 w = *(const float4*)&Qb[(rowBase + k0 + r) * E + col];
      Vt[r][c4 + 0] = w.x; Vt[r][c4 + 1] = w.y; Vt[r][c4 + 2] = w.z; Vt[r][c4 + 3] = w.w;
    }
    if (tid < 64) Ls[tid] = L[(size_t)bh * S + k0 + tid];
    __syncthreads();

    // scores s[q=ty*4+i][k=tx*4+j] -- same accumulation order as col_stats
    float s[4][4] = {};
    for (int d = 0; d < 64; ++d) {
      float a[4], bb[4];
      #pragma unroll
      for (int i = 0; i < 4; ++i) a[i] = Qq[ty * 4 + i][d];
      #pragma unroll
      for (int j = 0; j < 4; ++j) bb[j] = Kt[tx * 4 + j][d];
      #pragma unroll
      for (int i = 0; i < 4; ++i)
        #pragma unroll
        for (int j = 0; j < 4; ++j)
          s[i][j] += a[i] * bb[j];
    }
    float rl[4];
    #pragma unroll
    for (int j = 0; j < 4; ++j) rl[j] = 1.0f / Ls[tx * 4 + j];

    __syncthreads();   // prior iteration's Wl reads complete
    #pragma unroll
    for (int i = 0; i < 4; ++i)
      #pragma unroll
      for (int j = 0; j < 4; ++j)
        Wl[ty * 4 + i][tx * 4 + j] = __expf(s[i][j] * scale) * rl[j];
    __syncthreads();

    // oacc[q][d] += sum_k Wl[q][k] * Vt[k][d]
    for (int k = 0; k < 64; ++k) {
      float a[4], bb[4];
      #pragma unroll
      for (int i = 0; i < 4; ++i) a[i] = Wl[ty * 4 + i][k];
      #pragma unroll
      for (int j = 0; j < 4; ++j) bb[j] = Vt[k][tx * 4 + j];
      #pragma unroll
      for (int i = 0; i < 4; ++i)
        #pragma unroll
        for (int j = 0; j < 4; ++j)
          oacc[i][j] += a[i] * bb[j];
    }
  }

  #pragma unroll
  for (int i = 0; i < 4; ++i) {
    float4 o;
    o.x = oacc[i][0]; o.y = oacc[i][1]; o.z = oacc[i][2]; o.w = oacc[i][3];
    *(float4*)&O[(rowBase + q0 + ty * 4 + i) * E + h * 64 + tx * 4] = o;
  }
}

// ---------------------------------------------------------------------------
// inputs: 0=input_ids 1=W_q 2=b_q 3=W_k 4=b_k 5=W_v(unused) 6=b_v(unused)
//         7=W_o 8=b_o
// ws: Q[4096*1024] | K[4096*1024] | Oconcat[4096*1024] | L[64*1024]  (~50.6 MB)
// ---------------------------------------------------------------------------
extern "C" void kernel_launch(void* const* d_in, const int* in_sizes, int n_in,
                              void* d_out, int out_size, void* d_ws, size_t ws_size,
                              hipStream_t stream)
{
  const float* X  = (const float*)d_in[0];
  const float* Wq = (const float*)d_in[1];
  const float* bq = (const float*)d_in[2];
  const float* Wk = (const float*)d_in[3];
  const float* bk = (const float*)d_in[4];
  const float* Wo = (const float*)d_in[7];
  const float* bo = (const float*)d_in[8];
  float* out = (float*)d_out;

  const int Mrows = 4096;   // B*S
  const int E = 1024;

  float* Qbuf = (float*)d_ws;
  float* Kbuf = Qbuf + (size_t)Mrows * E;
  float* Obuf = Kbuf + (size_t)Mrows * E;
  float* Lbuf = Obuf + (size_t)Mrows * E;

  dim3 blk(256);
  // Q and K projections (per-head stacked weights, MODE 1)
  gemm64<1><<<dim3(16, 64), blk, 0, stream>>>(X, Wq, bq, Qbuf, Mrows, E, E);
  gemm64<1><<<dim3(16, 64), blk, 0, stream>>>(X, Wk, bk, Kbuf, Mrows, E, E);
  // column softmax denominators
  col_stats<<<dim3(16, 64), blk, 0, stream>>>(Qbuf, Kbuf, Lbuf);
  // attention output (v = q), concat-head layout
  attn_out<<<dim3(16, 64), blk, 0, stream>>>(Qbuf, Kbuf, Lbuf, Obuf);
  // final projection (MODE 0) + bias -> d_out
  gemm64<0><<<dim3(16, 64), blk, 0, stream>>>(Obuf, Wo, bo, out, Mrows, E, E);
}

// Round 2
// 252.284 us; speedup vs baseline: 3.9634x; 3.9634x over previous
//
#include <hip/hip_runtime.h>
#include <cstddef>

typedef __attribute__((ext_vector_type(8))) short bf16x8;     // MFMA A/B frag (8 bf16)
typedef __attribute__((ext_vector_type(4))) float f32x4;      // MFMA C/D frag
typedef __attribute__((ext_vector_type(8))) unsigned short us8;

__device__ __forceinline__ unsigned short f2bf(float f) {
  union { float f; unsigned int u; } v; v.f = f;
  unsigned int u = v.u;
  unsigned int r = (u + 0x7FFFu + ((u >> 16) & 1u)) >> 16;   // RNE
  return (unsigned short)r;
}

// ---------------------------------------------------------------------------
// One-time cast X (fp32 -> bf16), 4 elems/thread
// ---------------------------------------------------------------------------
__global__ __launch_bounds__(256) void cast_f32_bf16(
    const float* __restrict__ in, unsigned short* __restrict__ out)
{
  int i = (blockIdx.x * 256 + threadIdx.x) * 4;
  float4 v = *(const float4*)&in[i];
  ushort4 o;
  o.x = f2bf(v.x); o.y = f2bf(v.y); o.z = f2bf(v.z); o.w = f2bf(v.w);
  *(ushort4*)&out[i] = o;
}

// ---------------------------------------------------------------------------
// Weight transpose+cast: W -> Wt[N][K] bf16 (k contiguous).
// MODE 0: W is [K,N] fp32 row-major.  MODE 1: W is [H, K, 64] stacked (n=h*64+d).
// 64x64 tiles; block 256.
// ---------------------------------------------------------------------------
template<int MODE>
__global__ __launch_bounds__(256) void transpose_cast(
    const float* __restrict__ W, unsigned short* __restrict__ Wt, int K, int N)
{
  __shared__ __align__(16) unsigned short T[64 * 72];
  const int k0 = blockIdx.y * 64, n0 = blockIdx.x * 64;
  const int t = threadIdx.x;
  const int kr = t >> 4, n4 = (t & 15) * 4;
  #pragma unroll
  for (int i = 0; i < 4; ++i) {
    const int k = k0 + kr + i * 16;
    const float* src;
    if (MODE == 0) src = &W[(size_t)k * N + n0 + n4];
    else           src = &W[((size_t)(n0 >> 6) * K + k) * 64 + n4];
    float4 v = *(const float4*)src;
    T[(n4 + 0) * 72 + kr + i * 16] = f2bf(v.x);
    T[(n4 + 1) * 72 + kr + i * 16] = f2bf(v.y);
    T[(n4 + 2) * 72 + kr + i * 16] = f2bf(v.z);
    T[(n4 + 3) * 72 + kr + i * 16] = f2bf(v.w);
  }
  __syncthreads();
  const int n = t >> 2, kc = (t & 3) * 16;
  us8 o0 = *(const us8*)&T[n * 72 + kc];
  us8 o1 = *(const us8*)&T[n * 72 + kc + 8];
  *(us8*)&Wt[(size_t)(n0 + n) * K + k0 + kc] = o0;
  *(us8*)&Wt[(size_t)(n0 + n) * K + k0 + kc + 8] = o1;
}

// ---------------------------------------------------------------------------
// MFMA GEMM: C[m,n] = sum_k A[m,k]*Bt[n,k] + bias[n].
// A bf16 [M,K], Bt bf16 [N,K]. 128x128 tile, BK=32, 4 waves (2x2, 64x64 each).
// OUT_BF16: 1 -> bf16 out, 0 -> fp32 out.
// ---------------------------------------------------------------------------
template<int OUT_BF16>
__global__ __launch_bounds__(256) void gemm_bf16(
    const unsigned short* __restrict__ A, const unsigned short* __restrict__ Bt,
    const float* __restrict__ bias, void* __restrict__ C,
    int M, int N, int K)
{
  __shared__ __align__(16) unsigned short Asl[128 * 40];
  __shared__ __align__(16) unsigned short Bsl[128 * 40];
  const int tid = threadIdx.x;
  const int m0 = blockIdx.y * 128, n0 = blockIdx.x * 128;
  const int wave = tid >> 6, lane = tid & 63;
  const int wm = (wave & 1) * 64, wn = (wave >> 1) * 64;
  const int l15 = lane & 15, l4 = lane >> 4;
  const int srow = tid >> 1, skh = (tid & 1) * 16;

  f32x4 acc[4][4] = {};

  for (int kt = 0; kt < K; kt += 32) {
    us8 a0 = *(const us8*)&A[(size_t)(m0 + srow) * K + kt + skh];
    us8 a1 = *(const us8*)&A[(size_t)(m0 + srow) * K + kt + skh + 8];
    us8 b0 = *(const us8*)&Bt[(size_t)(n0 + srow) * K + kt + skh];
    us8 b1 = *(const us8*)&Bt[(size_t)(n0 + srow) * K + kt + skh + 8];
    __syncthreads();   // prior iteration's frag reads complete
    *(us8*)&Asl[srow * 40 + skh] = a0;
    *(us8*)&Asl[srow * 40 + skh + 8] = a1;
    *(us8*)&Bsl[srow * 40 + skh] = b0;
    *(us8*)&Bsl[srow * 40 + skh + 8] = b1;
    __syncthreads();
    bf16x8 af[4], bfv[4];
    #pragma unroll
    for (int mi = 0; mi < 4; ++mi)
      af[mi] = *(const bf16x8*)&Asl[(wm + mi * 16 + l15) * 40 + l4 * 8];
    #pragma unroll
    for (int nj = 0; nj < 4; ++nj)
      bfv[nj] = *(const bf16x8*)&Bsl[(wn + nj * 16 + l15) * 40 + l4 * 8];
    #pragma unroll
    for (int mi = 0; mi < 4; ++mi)
      #pragma unroll
      for (int nj = 0; nj < 4; ++nj)
        acc[mi][nj] = __builtin_amdgcn_mfma_f32_16x16x32_bf16(
            af[mi], bfv[nj], acc[mi][nj], 0, 0, 0);
  }

  #pragma unroll
  for (int mi = 0; mi < 4; ++mi) {
    #pragma unroll
    for (int nj = 0; nj < 4; ++nj) {
      const int row = m0 + wm + mi * 16 + l4 * 4;   // + r
      const int col = n0 + wn + nj * 16 + l15;
      const float bv = bias[col];
      #pragma unroll
      for (int r = 0; r < 4; ++r) {
        const float v = acc[mi][nj][r] + bv;
        if (OUT_BF16)
          ((unsigned short*)C)[(size_t)(row + r) * N + col] = f2bf(v);
        else
          ((float*)C)[(size_t)(row + r) * N + col] = v;
      }
    }
  }
}

// ---------------------------------------------------------------------------
// Column softmax denominators via MFMA.
// L[bh,k] = sum_q exp((K[k,:]·Q[q,:]) / 32).  Block: 64-k tile of one (b,h).
// S-GEMM: A = K-tile (m=k index), B = Q^T (contract over d). 4 waves, 16 k each.
// ---------------------------------------------------------------------------
__global__ __launch_bounds__(256) void col_stats(
    const unsigned short* __restrict__ Qb, const unsigned short* __restrict__ Kb,
    float* __restrict__ L)
{
  const int S = 1024, E = 1024;
  const float scale = 0.03125f;
  __shared__ __align__(16) unsigned short Ksl[64 * 72];
  __shared__ __align__(16) unsigned short Qsl[64 * 72];
  const int bh = blockIdx.y, b = bh >> 4, h = bh & 15;
  const int k0 = blockIdx.x * 64;
  const int tid = threadIdx.x, wave = tid >> 6, lane = tid & 63;
  const int l15 = lane & 15, l4 = lane >> 4;
  const size_t rowBase = (size_t)b * S;
  const int r = tid >> 2, c = (tid & 3) * 16;

  {
    const unsigned short* src = &Kb[(rowBase + k0 + r) * E + h * 64 + c];
    *(us8*)&Ksl[r * 72 + c] = *(const us8*)src;
    *(us8*)&Ksl[r * 72 + c + 8] = *(const us8*)(src + 8);
  }

  float Lacc[4] = {0.f, 0.f, 0.f, 0.f};
  for (int q0 = 0; q0 < S; q0 += 64) {
    __syncthreads();   // K staged (1st iter) / prior frag reads done
    const unsigned short* src = &Qb[(rowBase + q0 + r) * E + h * 64 + c];
    us8 v0 = *(const us8*)src, v1 = *(const us8*)(src + 8);
    *(us8*)&Qsl[r * 72 + c] = v0;
    *(us8*)&Qsl[r * 72 + c + 8] = v1;
    __syncthreads();

    f32x4 accs[4] = {};
    #pragma unroll
    for (int ds = 0; ds < 2; ++ds) {
      bf16x8 af = *(const bf16x8*)&Ksl[(wave * 16 + l15) * 72 + ds * 32 + l4 * 8];
      #pragma unroll
      for (int nj = 0; nj < 4; ++nj) {
        bf16x8 bv = *(const bf16x8*)&Qsl[(nj * 16 + l15) * 72 + ds * 32 + l4 * 8];
        accs[nj] = __builtin_amdgcn_mfma_f32_16x16x32_bf16(af, bv, accs[nj], 0, 0, 0);
      }
    }
    #pragma unroll
    for (int nj = 0; nj < 4; ++nj)
      #pragma unroll
      for (int rr = 0; rr < 4; ++rr)
        Lacc[rr] += __expf(accs[nj][rr] * scale);
  }

  // reduce over the 16 columns held across lanes (xor within low-4 lane bits)
  #pragma unroll
  for (int off = 1; off < 16; off <<= 1)
    #pragma unroll
    for (int rr = 0; rr < 4; ++rr)
      Lacc[rr] += __shfl_xor(Lacc[rr], off);
  if (l15 == 0) {
    #pragma unroll
    for (int rr = 0; rr < 4; ++rr)
      L[(size_t)bh * S + k0 + wave * 16 + l4 * 4 + rr] = Lacc[rr];
  }
}

// ---------------------------------------------------------------------------
// Attention output via MFMA (V = Q, column-normalized weights).
// Block: 64-q tile of one (b,h); streams k-tiles of 64.
// S-GEMM (contract d) -> P = exp(s/32)/L[k] -> LDS (bf16) -> O-GEMM (contract k).
// ---------------------------------------------------------------------------
__global__ __launch_bounds__(256) void attn_out(
    const unsigned short* __restrict__ Qb, const unsigned short* __restrict__ Kb,
    const float* __restrict__ L, unsigned short* __restrict__ O)
{
  const int S = 1024, E = 1024;
  const float scale = 0.03125f;
  __shared__ __align__(16) unsigned short Qsl[64 * 72];   // [q][d]
  __shared__ __align__(16) unsigned short Ksl[64 * 72];   // [k][d]
  __shared__ __align__(16) unsigned short Vtl[64 * 72];   // [d][k]  (V = Q rows)
  __shared__ __align__(16) unsigned short Psl[64 * 72];   // [q][k]
  __shared__ float Lls[64];
  const int bh = blockIdx.y, b = bh >> 4, h = bh & 15;
  const int q0 = blockIdx.x * 64;
  const int tid = threadIdx.x, wave = tid >> 6, lane = tid & 63;
  const int l15 = lane & 15, l4 = lane >> 4;
  const size_t rowBase = (size_t)b * S;
  const int r = tid >> 2, c = (tid & 3) * 16;
  const int dcol = tid & 63, kh = (tid >> 6) * 16;

  {
    const unsigned short* src = &Qb[(rowBase + q0 + r) * E + h * 64 + c];
    *(us8*)&Qsl[r * 72 + c] = *(const us8*)src;
    *(us8*)&Qsl[r * 72 + c + 8] = *(const us8*)(src + 8);
  }

  f32x4 acco[4] = {};
  for (int k0 = 0; k0 < S; k0 += 64) {
    __syncthreads();   // prior O-GEMM reads (Psl/Vtl) + Q staged on 1st iter
    {
      const unsigned short* src = &Kb[(rowBase + k0 + r) * E + h * 64 + c];
      *(us8*)&Ksl[r * 72 + c] = *(const us8*)src;
      *(us8*)&Ksl[r * 72 + c + 8] = *(const us8*)(src + 8);
    }
    {
      us8 t0, t1;
      #pragma unroll
      for (int kk = 0; kk < 8; ++kk)
        t0[kk] = Qb[(rowBase + k0 + kh + kk) * E + h * 64 + dcol];
      #pragma unroll
      for (int kk = 0; kk < 8; ++kk)
        t1[kk] = Qb[(rowBase + k0 + kh + 8 + kk) * E + h * 64 + dcol];
      *(us8*)&Vtl[dcol * 72 + kh] = t0;
      *(us8*)&Vtl[dcol * 72 + kh + 8] = t1;
    }
    if (tid < 64) Lls[tid] = L[(size_t)bh * S + k0 + tid];
    __syncthreads();

    // S-GEMM: s[q = wave*16 strip][k-local 0..63]
    f32x4 accs[4] = {};
    #pragma unroll
    for (int ds = 0; ds < 2; ++ds) {
      bf16x8 af = *(const bf16x8*)&Qsl[(wave * 16 + l15) * 72 + ds * 32 + l4 * 8];
      #pragma unroll
      for (int nj = 0; nj < 4; ++nj) {
        bf16x8 bv = *(const bf16x8*)&Ksl[(nj * 16 + l15) * 72 + ds * 32 + l4 * 8];
        accs[nj] = __builtin_amdgcn_mfma_f32_16x16x32_bf16(af, bv, accs[nj], 0, 0, 0);
      }
    }
    // P = exp(s/32)/L[k] -> Psl (C-layout scatter, bf16)
    #pragma unroll
    for (int nj = 0; nj < 4; ++nj) {
      const float rl = 1.0f / Lls[nj * 16 + l15];
      #pragma unroll
      for (int rr = 0; rr < 4; ++rr) {
        const float w = __expf(accs[nj][rr] * scale) * rl;
        Psl[(wave * 16 + l4 * 4 + rr) * 72 + nj * 16 + l15] = f2bf(w);
      }
    }
    __syncthreads();

    // O-GEMM: acco[q][d] += P[q][k] * V[k][d]
    #pragma unroll
    for (int ks = 0; ks < 2; ++ks) {
      bf16x8 af = *(const bf16x8*)&Psl[(wave * 16 + l15) * 72 + ks * 32 + l4 * 8];
      #pragma unroll
      for (int nj = 0; nj < 4; ++nj) {
        bf16x8 bv = *(const bf16x8*)&Vtl[(nj * 16 + l15) * 72 + ks * 32 + l4 * 8];
        acco[nj] = __builtin_amdgcn_mfma_f32_16x16x32_bf16(af, bv, acco[nj], 0, 0, 0);
      }
    }
  }

  #pragma unroll
  for (int nj = 0; nj < 4; ++nj)
    #pragma unroll
    for (int rr = 0; rr < 4; ++rr)
      O[(rowBase + q0 + wave * 16 + l4 * 4 + rr) * E + h * 64 + nj * 16 + l15] =
          f2bf(acco[nj][rr]);
}

// ---------------------------------------------------------------------------
// inputs: 0=X 1=W_q 2=b_q 3=W_k 4=b_k 5=W_v 6=b_v 7=W_o 8=b_o
// ws (bf16 elems): Xbf[4M] Wqt[1M] Wkt[1M] Wot[1M] Qb[4M] Kb[4M] Ob[4M] | L fp32[64K]
// total ~38.25 MB
// ---------------------------------------------------------------------------
extern "C" void kernel_launch(void* const* d_in, const int* in_sizes, int n_in,
                              void* d_out, int out_size, void* d_ws, size_t ws_size,
                              hipStream_t stream)
{
  const float* X  = (const float*)d_in[0];
  const float* Wq = (const float*)d_in[1];
  const float* bq = (const float*)d_in[2];
  const float* Wk = (const float*)d_in[3];
  const float* bk = (const float*)d_in[4];
  const float* Wo = (const float*)d_in[7];
  const float* bo = (const float*)d_in[8];

  const int Mr = 4096, E = 1024;
  unsigned short* Xbf = (unsigned short*)d_ws;
  unsigned short* Wqt = Xbf + (size_t)Mr * E;
  unsigned short* Wkt = Wqt + (size_t)E * E;
  unsigned short* Wot = Wkt + (size_t)E * E;
  unsigned short* Qb  = Wot + (size_t)E * E;
  unsigned short* Kb  = Qb + (size_t)Mr * E;
  unsigned short* Ob  = Kb + (size_t)Mr * E;
  float* Lbuf = (float*)(Ob + (size_t)Mr * E);

  cast_f32_bf16<<<dim3(Mr * E / 1024), dim3(256), 0, stream>>>(X, Xbf);
  transpose_cast<1><<<dim3(16, 16), dim3(256), 0, stream>>>(Wq, Wqt, E, E);
  transpose_cast<1><<<dim3(16, 16), dim3(256), 0, stream>>>(Wk, Wkt, E, E);
  transpose_cast<0><<<dim3(16, 16), dim3(256), 0, stream>>>(Wo, Wot, E, E);

  gemm_bf16<1><<<dim3(8, 32), dim3(256), 0, stream>>>(Xbf, Wqt, bq, (void*)Qb, Mr, E, E);
  gemm_bf16<1><<<dim3(8, 32), dim3(256), 0, stream>>>(Xbf, Wkt, bk, (void*)Kb, Mr, E, E);

  col_stats<<<dim3(16, 64), dim3(256), 0, stream>>>(Qb, Kb, Lbuf);
  attn_out<<<dim3(16, 64), dim3(256), 0, stream>>>(Qb, Kb, Lbuf, Ob);

  gemm_bf16<0><<<dim3(8, 32), dim3(256), 0, stream>>>(Ob, Wot, bo, d_out, Mr, E, E);
}

// Round 3
// 231.395 us; speedup vs baseline: 4.3212x; 1.0903x over previous
//
#include <hip/hip_runtime.h>
#include <cstddef>

typedef __attribute__((ext_vector_type(8))) short bf16x8;     // MFMA A/B frag
typedef __attribute__((ext_vector_type(4))) float f32x4;      // MFMA C/D frag
typedef __attribute__((ext_vector_type(8))) unsigned short us8;
typedef __attribute__((ext_vector_type(4))) unsigned short us4;

#define MFMA(a, b, c) __builtin_amdgcn_mfma_f32_16x16x32_bf16((a), (b), (c), 0, 0, 0)

__device__ __forceinline__ unsigned short f2bf(float f) {
  union { float f; unsigned int u; } v; v.f = f;
  unsigned int u = v.u;
  return (unsigned short)((u + 0x7FFFu + ((u >> 16) & 1u)) >> 16);   // RNE
}
__device__ __forceinline__ float bf2f(unsigned short u) {
  union { unsigned int u; float f; } v; v.u = ((unsigned int)u) << 16; return v.f;
}
// async global->LDS, 16B per lane. LDS dest = wave-uniform base + lane*16,
// so every tile staged this way is linear in (tid*8) ushort offsets.
__device__ __forceinline__ void glds16(const void* g, void* l) {
  __builtin_amdgcn_global_load_lds(
      (const __attribute__((address_space(1))) unsigned int*)g,
      (__attribute__((address_space(3))) unsigned int*)l, 16, 0, 0);
}

// exp(s/32) == exp2(s * (log2e/32))
#define EXC 0.04508422002721defp
static __device__ const float kEXC = 0.0450842200277256f;

// ---------------------------------------------------------------------------
// One-time cast X (fp32 -> bf16), 4 elems/thread
// ---------------------------------------------------------------------------
__global__ __launch_bounds__(256) void cast_f32_bf16(
    const float* __restrict__ in, unsigned short* __restrict__ out)
{
  int i = (blockIdx.x * 256 + threadIdx.x) * 4;
  float4 v = *(const float4*)&in[i];
  ushort4 o;
  o.x = f2bf(v.x); o.y = f2bf(v.y); o.z = f2bf(v.z); o.w = f2bf(v.w);
  *(ushort4*)&out[i] = o;
}

// ---------------------------------------------------------------------------
// Weight transpose+cast: W -> Wt[N][K] bf16 (k contiguous).
// MODE 0: W is [K,N] fp32.  MODE 1: W is [H,K,64] stacked (n = h*64+d).
// ---------------------------------------------------------------------------
template<int MODE>
__global__ __launch_bounds__(256) void transpose_cast(
    const float* __restrict__ W, unsigned short* __restrict__ Wt, int K, int N)
{
  __shared__ __align__(16) unsigned short T[64 * 72];
  const int k0 = blockIdx.y * 64, n0 = blockIdx.x * 64;
  const int t = threadIdx.x;
  const int kr = t >> 4, n4 = (t & 15) * 4;
  #pragma unroll
  for (int i = 0; i < 4; ++i) {
    const int k = k0 + kr + i * 16;
    const float* src;
    if (MODE == 0) src = &W[(size_t)k * N + n0 + n4];
    else           src = &W[((size_t)(n0 >> 6) * K + k) * 64 + n4];
    float4 v = *(const float4*)src;
    T[(n4 + 0) * 72 + kr + i * 16] = f2bf(v.x);
    T[(n4 + 1) * 72 + kr + i * 16] = f2bf(v.y);
    T[(n4 + 2) * 72 + kr + i * 16] = f2bf(v.z);
    T[(n4 + 3) * 72 + kr + i * 16] = f2bf(v.w);
  }
  __syncthreads();
  const int n = t >> 2, kc = (t & 3) * 16;
  us8 o0 = *(const us8*)&T[n * 72 + kc];
  us8 o1 = *(const us8*)&T[n * 72 + kc + 8];
  *(us8*)&Wt[(size_t)(n0 + n) * K + k0 + kc] = o0;
  *(us8*)&Wt[(size_t)(n0 + n) * K + k0 + kc + 8] = o1;
}

// ---------------------------------------------------------------------------
// m97-style MFMA GEMM: C[m,n] = sum_k A[m,k]*Bt[n,k] + bias[n].
// 128x128 tile, BK=32, unpadded [128][32] LDS, global_load_lds width-16.
// SPLIT=1: N=2048, bf16 out, cols <1024 -> out0 (bias0), else out1 (bias1).
// SPLIT=0: fp32 out -> out0 + bias0.
// ---------------------------------------------------------------------------
template<int SPLIT>
__global__ __launch_bounds__(256) void gemm_m97(
    const unsigned short* __restrict__ A, const unsigned short* __restrict__ Bt,
    const float* __restrict__ bias0, const float* __restrict__ bias1,
    void* __restrict__ out0, void* __restrict__ out1, int N, int K)
{
  __shared__ __align__(16) unsigned short Asl[128 * 32];
  __shared__ __align__(16) unsigned short Bsl[128 * 32];
  const int tid = threadIdx.x;
  const int m0 = blockIdx.y * 128, n0 = blockIdx.x * 128;
  const int wave = tid >> 6, lane = tid & 63;
  const int wm = (wave & 1) * 64, wn = (wave >> 1) * 64;
  const int l15 = lane & 15, l4 = lane >> 4;
  const int srow = tid >> 2, scol = (tid & 3) * 8;
  const unsigned short* ga = &A[(size_t)(m0 + srow) * K + scol];
  const unsigned short* gb = &Bt[(size_t)(n0 + srow) * K + scol];
  const size_t half = (size_t)64 * K;

  f32x4 acc[4][4] = {};
  for (int kt = 0; kt < K; kt += 32) {
    __syncthreads();                       // prior frag reads done
    glds16(ga + kt,        &Asl[tid * 8]);
    glds16(ga + half + kt, &Asl[(tid + 256) * 8]);
    glds16(gb + kt,        &Bsl[tid * 8]);
    glds16(gb + half + kt, &Bsl[(tid + 256) * 8]);
    __syncthreads();                       // staging complete (vmcnt0 drain)
    bf16x8 af[4], bfv[4];
    #pragma unroll
    for (int mi = 0; mi < 4; ++mi)
      af[mi] = *(const bf16x8*)&Asl[(wm + mi * 16 + l15) * 32 + l4 * 8];
    #pragma unroll
    for (int nj = 0; nj < 4; ++nj)
      bfv[nj] = *(const bf16x8*)&Bsl[(wn + nj * 16 + l15) * 32 + l4 * 8];
    #pragma unroll
    for (int mi = 0; mi < 4; ++mi)
      #pragma unroll
      for (int nj = 0; nj < 4; ++nj)
        acc[mi][nj] = MFMA(af[mi], bfv[nj], acc[mi][nj]);
  }

  #pragma unroll
  for (int mi = 0; mi < 4; ++mi) {
    #pragma unroll
    for (int nj = 0; nj < 4; ++nj) {
      const int row = m0 + wm + mi * 16 + l4 * 4;
      const int col = n0 + wn + nj * 16 + l15;
      if (SPLIT) {
        const int qside = (col < 1024);
        const int lc = qside ? col : col - 1024;
        const float bv = qside ? bias0[lc] : bias1[lc];
        unsigned short* dst = qside ? (unsigned short*)out0 : (unsigned short*)out1;
        #pragma unroll
        for (int r = 0; r < 4; ++r)
          dst[(size_t)(row + r) * 1024 + lc] = f2bf(acc[mi][nj][r] + bv);
      } else {
        const float bv = bias0[col];
        #pragma unroll
        for (int r = 0; r < 4; ++r)
          ((float*)out0)[(size_t)(row + r) * N + col] = acc[mi][nj][r] + bv;
      }
    }
  }
}

// ---------------------------------------------------------------------------
// Column softmax denominators: L[bh,k] = sum_q exp2((K[k,:].Q[q,:])*EXC).
// Block: 64-k tile of one (b,h); waves split k (16 each); 128-q chunks,
// double-buffered via global_load_lds, 1 barrier/iter.
// ---------------------------------------------------------------------------
__global__ __launch_bounds__(256) void col_stats(
    const unsigned short* __restrict__ Qb, const unsigned short* __restrict__ Kb,
    float* __restrict__ L)
{
  const int S = 1024, E = 1024;
  __shared__ __align__(16) unsigned short Ks[2][64 * 32];       // [dhalf]
  __shared__ __align__(16) unsigned short Qs[2][2][128 * 32];   // [buf][dhalf]
  const int bh = blockIdx.y, b = bh >> 4, h = bh & 15;
  const int k0 = blockIdx.x * 64;
  const int tid = threadIdx.x, wave = tid >> 6, lane = tid & 63;
  const int l15 = lane & 15, l4 = lane >> 4;
  const size_t rowBase = (size_t)b * S;
  const int srow = tid >> 2, scol = (tid & 3) * 8;

  glds16(&Kb[(rowBase + k0 + srow) * E + h * 64 + scol],      &Ks[0][tid * 8]);
  glds16(&Kb[(rowBase + k0 + srow) * E + h * 64 + 32 + scol], &Ks[1][tid * 8]);
  #pragma unroll
  for (int ds = 0; ds < 2; ++ds) {
    glds16(&Qb[(rowBase + srow) * E + h * 64 + ds * 32 + scol],      &Qs[0][ds][tid * 8]);
    glds16(&Qb[(rowBase + 64 + srow) * E + h * 64 + ds * 32 + scol], &Qs[0][ds][(tid + 256) * 8]);
  }

  float Lacc[4] = {};
  for (int it = 0; it < 8; ++it) {
    const int cur = it & 1;
    __syncthreads();                 // buf[cur] staged; prior reads of buf[1-cur] done
    if (it < 7) {
      const int q1 = (it + 1) * 128;
      #pragma unroll
      for (int ds = 0; ds < 2; ++ds) {
        glds16(&Qb[(rowBase + q1 + srow) * E + h * 64 + ds * 32 + scol],
               &Qs[1 - cur][ds][tid * 8]);
        glds16(&Qb[(rowBase + q1 + 64 + srow) * E + h * 64 + ds * 32 + scol],
               &Qs[1 - cur][ds][(tid + 256) * 8]);
      }
    }
    f32x4 accs[8] = {};
    #pragma unroll
    for (int ds = 0; ds < 2; ++ds) {
      bf16x8 af = *(const bf16x8*)&Ks[ds][(wave * 16 + l15) * 32 + l4 * 8];
      #pragma unroll
      for (int nj = 0; nj < 8; ++nj) {
        bf16x8 bv = *(const bf16x8*)&Qs[cur][ds][(nj * 16 + l15) * 32 + l4 * 8];
        accs[nj] = MFMA(af, bv, accs[nj]);
      }
    }
    #pragma unroll
    for (int nj = 0; nj < 8; ++nj)
      #pragma unroll
      for (int rr = 0; rr < 4; ++rr)
        Lacc[rr] += exp2f(accs[nj][rr] * kEXC);
  }
  #pragma unroll
  for (int off = 1; off < 16; off <<= 1)
    #pragma unroll
    for (int rr = 0; rr < 4; ++rr)
      Lacc[rr] += __shfl_xor(Lacc[rr], off);
  if (l15 == 0) {
    #pragma unroll
    for (int rr = 0; rr < 4; ++rr)
      L[(size_t)bh * S + k0 + wave * 16 + l4 * 4 + rr] = Lacc[rr];
  }
}

// ---------------------------------------------------------------------------
// Build Vt[bh*64+d][k] = Q[b,k,h*64+d] / L[bh,k]   (bf16, k contiguous).
// 64x64 tiles, LDS transpose; scale applied on the coalesced-read side.
// ---------------------------------------------------------------------------
__global__ __launch_bounds__(256) void build_vt(
    const unsigned short* __restrict__ Qb, const float* __restrict__ L,
    unsigned short* __restrict__ Vt)
{
  __shared__ __align__(16) unsigned short T[64 * 72];
  const int bh = blockIdx.y, b = bh >> 4, h = bh & 15;
  const int k0 = blockIdx.x * 64;
  const int t = threadIdx.x;
  const int row = t >> 2, d16 = (t & 3) * 16;
  const size_t rowBase = (size_t)b * 1024;
  const float rl = 1.0f / L[(size_t)bh * 1024 + k0 + row];
  const unsigned short* src = &Qb[(rowBase + k0 + row) * 1024 + h * 64 + d16];
  us8 v0 = *(const us8*)src, v1 = *(const us8*)(src + 8);
  #pragma unroll
  for (int j = 0; j < 8; ++j) T[(d16 + j) * 72 + row]     = f2bf(bf2f(v0[j]) * rl);
  #pragma unroll
  for (int j = 0; j < 8; ++j) T[(d16 + 8 + j) * 72 + row] = f2bf(bf2f(v1[j]) * rl);
  __syncthreads();
  const int d = t >> 2, kh = (t & 3) * 16;
  unsigned short* dst = &Vt[((size_t)bh * 64 + d) * 1024 + k0 + kh];
  *(us8*)dst       = *(const us8*)&T[d * 72 + kh];
  *(us8*)(dst + 8) = *(const us8*)&T[d * 72 + kh + 8];
}

// ---------------------------------------------------------------------------
// Attention output. Block: 128-q tile of one (b,h); streams 16 k-tiles of 64.
// S^T-GEMM (A=K, B=Q; C-layout gives 4 contiguous k per lane) -> exp2 ->
// packed ds_write_b64 into Ps[q][k] -> O-GEMM (A=Ps, B=Vt[d][k]).
// Single-buffered; glds issue points give overlap: Vs || S-GEMM, Ks || O-GEMM.
// LDS 48 KB.
// ---------------------------------------------------------------------------
__global__ __launch_bounds__(256) void attn_out(
    const unsigned short* __restrict__ Qb, const unsigned short* __restrict__ Kb,
    const unsigned short* __restrict__ VtH, unsigned short* __restrict__ O)
{
  const int S = 1024, E = 1024;
  __shared__ __align__(16) unsigned short Qs[2][128 * 32];   // [dhalf][q][d]
  __shared__ __align__(16) unsigned short Ks[2][64 * 32];    // [dhalf][k][d]
  __shared__ __align__(16) unsigned short Vs[2][64 * 32];    // [khalf][d][k]
  __shared__ __align__(16) unsigned short Ps[2][128 * 32];   // [khalf][q][k]
  const int bh = blockIdx.y, b = bh >> 4, h = bh & 15;
  const int q0 = blockIdx.x * 128;
  const int tid = threadIdx.x, wave = tid >> 6, lane = tid & 63;
  const int l15 = lane & 15, l4 = lane >> 4;
  const size_t rowBase = (size_t)b * S;
  const int srow = tid >> 2, scol = (tid & 3) * 8;

  #pragma unroll
  for (int ds = 0; ds < 2; ++ds) {
    glds16(&Qb[(rowBase + q0 + srow) * E + h * 64 + ds * 32 + scol],      &Qs[ds][tid * 8]);
    glds16(&Qb[(rowBase + q0 + 64 + srow) * E + h * 64 + ds * 32 + scol], &Qs[ds][(tid + 256) * 8]);
  }
  glds16(&Kb[(rowBase + srow) * E + h * 64 + scol],      &Ks[0][tid * 8]);
  glds16(&Kb[(rowBase + srow) * E + h * 64 + 32 + scol], &Ks[1][tid * 8]);

  f32x4 acco[2][4] = {};
  for (int it = 0; it < 16; ++it) {
    const int k0 = it * 64;
    __syncthreads();   // B1: Ks(it)+Qs staged; O-GEMM(it-1) reads of Ps/Vs done
    glds16(&VtH[((size_t)bh * 64 + srow) * S + k0 + scol],      &Vs[0][tid * 8]);
    glds16(&VtH[((size_t)bh * 64 + srow) * S + k0 + 32 + scol], &Vs[1][tid * 8]);

    f32x4 accs[4][2] = {};
    #pragma unroll
    for (int ds = 0; ds < 2; ++ds) {
      bf16x8 bq0 = *(const bf16x8*)&Qs[ds][(wave * 32 + l15) * 32 + l4 * 8];
      bf16x8 bq1 = *(const bf16x8*)&Qs[ds][(wave * 32 + 16 + l15) * 32 + l4 * 8];
      #pragma unroll
      for (int mi = 0; mi < 4; ++mi) {
        bf16x8 ak = *(const bf16x8*)&Ks[ds][(mi * 16 + l15) * 32 + l4 * 8];
        accs[mi][0] = MFMA(ak, bq0, accs[mi][0]);
        accs[mi][1] = MFMA(ak, bq1, accs[mi][1]);
      }
    }
    // lane holds s[k=mi*16+l4*4+rr][q=wave*32+nj*16+l15]; 4 k contiguous -> b64
    #pragma unroll
    for (int mi = 0; mi < 4; ++mi) {
      #pragma unroll
      for (int nj = 0; nj < 2; ++nj) {
        const int q = wave * 32 + nj * 16 + l15;
        us4 pk;
        #pragma unroll
        for (int rr = 0; rr < 4; ++rr)
          pk[rr] = f2bf(exp2f(accs[mi][nj][rr] * kEXC));
        *(us4*)&Ps[mi >> 1][q * 32 + (mi & 1) * 16 + l4 * 4] = pk;
      }
    }
    __syncthreads();   // B2: Ps visible; Vs(it) drained
    if (it < 15) {
      glds16(&Kb[(rowBase + k0 + 64 + srow) * E + h * 64 + scol],      &Ks[0][tid * 8]);
      glds16(&Kb[(rowBase + k0 + 64 + srow) * E + h * 64 + 32 + scol], &Ks[1][tid * 8]);
    }
    #pragma unroll
    for (int ks = 0; ks < 2; ++ks) {
      bf16x8 ap0 = *(const bf16x8*)&Ps[ks][(wave * 32 + l15) * 32 + l4 * 8];
      bf16x8 ap1 = *(const bf16x8*)&Ps[ks][(wave * 32 + 16 + l15) * 32 + l4 * 8];
      #pragma unroll
      for (int nj = 0; nj < 4; ++nj) {
        bf16x8 bv = *(const bf16x8*)&Vs[ks][(nj * 16 + l15) * 32 + l4 * 8];
        acco[0][nj] = MFMA(ap0, bv, acco[0][nj]);
        acco[1][nj] = MFMA(ap1, bv, acco[1][nj]);
      }
    }
  }

  #pragma unroll
  for (int mi2 = 0; mi2 < 2; ++mi2)
    #pragma unroll
    for (int nj = 0; nj < 4; ++nj)
      #pragma unroll
      for (int rr = 0; rr < 4; ++rr)
        O[(rowBase + q0 + wave * 32 + mi2 * 16 + l4 * 4 + rr) * E + h * 64 + nj * 16 + l15] =
            f2bf(acco[mi2][nj][rr]);
}

// ---------------------------------------------------------------------------
// inputs: 0=X 1=W_q 2=b_q 3=W_k 4=b_k 5=W_v 6=b_v 7=W_o 8=b_o
// ws (bf16): Xbf[4M] Wqkt[2M] Wot[1M] Qb[4M] Kb[4M] Ob[4M] Vt[4M] | L f32[64K]
// total ~46.25 MB
// ---------------------------------------------------------------------------
extern "C" void kernel_launch(void* const* d_in, const int* in_sizes, int n_in,
                              void* d_out, int out_size, void* d_ws, size_t ws_size,
                              hipStream_t stream)
{
  const float* X  = (const float*)d_in[0];
  const float* Wq = (const float*)d_in[1];
  const float* bq = (const float*)d_in[2];
  const float* Wk = (const float*)d_in[3];
  const float* bk = (const float*)d_in[4];
  const float* Wo = (const float*)d_in[7];
  const float* bo = (const float*)d_in[8];

  const int Mr = 4096, E = 1024;
  unsigned short* Xbf  = (unsigned short*)d_ws;
  unsigned short* Wqkt = Xbf  + (size_t)Mr * E;
  unsigned short* Wot  = Wqkt + (size_t)2 * E * E;
  unsigned short* Qb   = Wot  + (size_t)E * E;
  unsigned short* Kb   = Qb   + (size_t)Mr * E;
  unsigned short* Ob   = Kb   + (size_t)Mr * E;
  unsigned short* Vt   = Ob   + (size_t)Mr * E;
  float* Lbuf = (float*)(Vt + (size_t)Mr * E);

  cast_f32_bf16<<<dim3(Mr * E / 1024), dim3(256), 0, stream>>>(X, Xbf);
  transpose_cast<1><<<dim3(16, 16), dim3(256), 0, stream>>>(Wq, Wqkt, E, E);
  transpose_cast<1><<<dim3(16, 16), dim3(256), 0, stream>>>(Wk, Wqkt + (size_t)E * E, E, E);
  transpose_cast<0><<<dim3(16, 16), dim3(256), 0, stream>>>(Wo, Wot, E, E);

  // fused Q|K projection: N=2048, split epilogue
  gemm_m97<1><<<dim3(16, 32), dim3(256), 0, stream>>>(
      Xbf, Wqkt, bq, bk, (void*)Qb, (void*)Kb, 2048, E);

  col_stats<<<dim3(16, 64), dim3(256), 0, stream>>>(Qb, Kb, Lbuf);
  build_vt<<<dim3(16, 64), dim3(256), 0, stream>>>(Qb, Lbuf, Vt);
  attn_out<<<dim3(8, 64), dim3(256), 0, stream>>>(Qb, Kb, Vt, Ob);

  gemm_m97<0><<<dim3(8, 32), dim3(256), 0, stream>>>(
      Ob, Wot, bo, nullptr, d_out, nullptr, E, E);
}

// Round 4
// 208.711 us; speedup vs baseline: 4.7908x; 1.1087x over previous
//
#include <hip/hip_runtime.h>
#include <cstddef>

typedef __attribute__((ext_vector_type(8))) short bf16x8;     // MFMA A/B frag
typedef __attribute__((ext_vector_type(4))) float f32x4;      // MFMA C/D frag
typedef __attribute__((ext_vector_type(8))) unsigned short us8;

#define MFMA(a, b, c) __builtin_amdgcn_mfma_f32_16x16x32_bf16((a), (b), (c), 0, 0, 0)

#define KEXC 0.0450842200277256f   // log2(e)/32  -> exp(s/32) = exp2(s*KEXC)

__device__ __forceinline__ unsigned short f2bf(float f) {   // RNE
  union { float f; unsigned int u; } v; v.f = f;
  return (unsigned short)((v.u + 0x7FFFu + ((v.u >> 16) & 1u)) >> 16);
}
__device__ __forceinline__ float bf2f(unsigned short u) {
  union { unsigned int u; float f; } v; v.u = ((unsigned int)u) << 16; return v.f;
}
// pack two floats to bf16 pair, round-half-up (cheap: 2 add + shr + and + or)
__device__ __forceinline__ unsigned int pack_bf2(float a, float b) {
  union { float f; unsigned int u; } x, y; x.f = a; y.f = b;
  return ((x.u + 0x8000u) >> 16) | ((y.u + 0x8000u) & 0xFFFF0000u);
}
// async global->LDS, 16B/lane; LDS dest = wave-uniform base + lane*16
__device__ __forceinline__ void glds16(const void* g, void* l) {
  __builtin_amdgcn_global_load_lds(
      (const __attribute__((address_space(1))) unsigned int*)g,
      (__attribute__((address_space(3))) unsigned int*)l, 16, 0, 0);
}

// ---------------------------------------------------------------------------
// prep: blocks [0,4096): cast X fp32->bf16 (1024 elems/block).
//       blocks [4096,4864): transpose+cast weights -> Wt[N][K] bf16.
//         +0..255: Wq (stacked [H,K,64]); +256..511: Wk (stacked, scaled KEXC);
//         +512..767: Wo ([K,N] row-major).
// ---------------------------------------------------------------------------
__global__ __launch_bounds__(256) void prep(
    const float* __restrict__ X,  const float* __restrict__ Wq,
    const float* __restrict__ Wk, const float* __restrict__ Wo,
    unsigned short* __restrict__ Xbf, unsigned short* __restrict__ Wqkt,
    unsigned short* __restrict__ Wot)
{
  __shared__ __align__(16) unsigned short T[64 * 72];
  const int t = threadIdx.x;
  int blk = blockIdx.x;
  if (blk < 4096) {
    int i = (blk * 256 + t) * 4;
    float4 v = *(const float4*)&X[i];
    ushort4 o;
    o.x = f2bf(v.x); o.y = f2bf(v.y); o.z = f2bf(v.z); o.w = f2bf(v.w);
    *(ushort4*)&Xbf[i] = o;
    return;
  }
  blk -= 4096;
  const float* W; unsigned short* dst; int mode; float scale = 1.0f;
  if (blk < 256)      { W = Wq; dst = Wqkt;                 mode = 1; }
  else if (blk < 512) { W = Wk; dst = Wqkt + 1024 * 1024;   mode = 1; scale = KEXC; blk -= 256; }
  else                { W = Wo; dst = Wot;                  mode = 0; blk -= 512; }
  const int K = 1024, N = 1024;
  const int n0 = (blk & 15) * 64, k0 = (blk >> 4) * 64;
  const int kr = t >> 4, n4 = (t & 15) * 4;
  #pragma unroll
  for (int i = 0; i < 4; ++i) {
    const int k = k0 + kr + i * 16;
    const float* src = (mode == 0) ? &W[(size_t)k * N + n0 + n4]
                                   : &W[((size_t)(n0 >> 6) * K + k) * 64 + n4];
    float4 v = *(const float4*)src;
    T[(n4 + 0) * 72 + kr + i * 16] = f2bf(v.x * scale);
    T[(n4 + 1) * 72 + kr + i * 16] = f2bf(v.y * scale);
    T[(n4 + 2) * 72 + kr + i * 16] = f2bf(v.z * scale);
    T[(n4 + 3) * 72 + kr + i * 16] = f2bf(v.w * scale);
  }
  __syncthreads();
  const int n = t >> 2, kc = (t & 3) * 16;
  us8 o0 = *(const us8*)&T[n * 72 + kc];
  us8 o1 = *(const us8*)&T[n * 72 + kc + 8];
  *(us8*)&dst[(size_t)(n0 + n) * K + k0 + kc] = o0;
  *(us8*)&dst[(size_t)(n0 + n) * K + k0 + kc + 8] = o1;
}

// ---------------------------------------------------------------------------
// m97-style MFMA GEMM: C[m,n] = sum_k A[m,k]*Bt[n,k] + bias.
// SPLIT=1: N=2048, bf16 out; cols<1024 -> out0+bias0; else out1+bias1*bs1.
// SPLIT=0: fp32 out -> out0+bias0.
// ---------------------------------------------------------------------------
template<int SPLIT>
__global__ __launch_bounds__(256) void gemm_m97(
    const unsigned short* __restrict__ A, const unsigned short* __restrict__ Bt,
    const float* __restrict__ bias0, const float* __restrict__ bias1,
    void* __restrict__ out0, void* __restrict__ out1, int N, int K, float bs1)
{
  __shared__ __align__(16) unsigned short Asl[128 * 32];
  __shared__ __align__(16) unsigned short Bsl[128 * 32];
  const int tid = threadIdx.x;
  const int m0 = blockIdx.y * 128, n0 = blockIdx.x * 128;
  const int wave = tid >> 6, lane = tid & 63;
  const int wm = (wave & 1) * 64, wn = (wave >> 1) * 64;
  const int l15 = lane & 15, l4 = lane >> 4;
  const int srow = tid >> 2, scol = (tid & 3) * 8;
  const unsigned short* ga = &A[(size_t)(m0 + srow) * K + scol];
  const unsigned short* gb = &Bt[(size_t)(n0 + srow) * K + scol];
  const size_t half = (size_t)64 * K;

  f32x4 acc[4][4] = {};
  for (int kt = 0; kt < K; kt += 32) {
    __syncthreads();
    glds16(ga + kt,        &Asl[tid * 8]);
    glds16(ga + half + kt, &Asl[(tid + 256) * 8]);
    glds16(gb + kt,        &Bsl[tid * 8]);
    glds16(gb + half + kt, &Bsl[(tid + 256) * 8]);
    __syncthreads();
    bf16x8 af[4], bfv[4];
    #pragma unroll
    for (int mi = 0; mi < 4; ++mi)
      af[mi] = *(const bf16x8*)&Asl[(wm + mi * 16 + l15) * 32 + l4 * 8];
    #pragma unroll
    for (int nj = 0; nj < 4; ++nj)
      bfv[nj] = *(const bf16x8*)&Bsl[(wn + nj * 16 + l15) * 32 + l4 * 8];
    #pragma unroll
    for (int mi = 0; mi < 4; ++mi)
      #pragma unroll
      for (int nj = 0; nj < 4; ++nj)
        acc[mi][nj] = MFMA(af[mi], bfv[nj], acc[mi][nj]);
  }

  #pragma unroll
  for (int mi = 0; mi < 4; ++mi) {
    #pragma unroll
    for (int nj = 0; nj < 4; ++nj) {
      const int row = m0 + wm + mi * 16 + l4 * 4;
      const int col = n0 + wn + nj * 16 + l15;
      if (SPLIT) {
        const int qside = (col < 1024);
        const int lc = qside ? col : col - 1024;
        const float bv = qside ? bias0[lc] : bias1[lc] * bs1;
        unsigned short* dst = qside ? (unsigned short*)out0 : (unsigned short*)out1;
        #pragma unroll
        for (int r = 0; r < 4; ++r)
          dst[(size_t)(row + r) * 1024 + lc] = f2bf(acc[mi][nj][r] + bv);
      } else {
        const float bv = bias0[col];
        #pragma unroll
        for (int r = 0; r < 4; ++r)
          ((float*)out0)[(size_t)(row + r) * N + col] = acc[mi][nj][r] + bv;
      }
    }
  }
}

// ---------------------------------------------------------------------------
// cs_vt: per (bh, k-tile64): L[k] = sum_q exp2(K'[k,:].Q[q,:]), then
//        Vt[bh*64+d][k] = Q[k,d] / L[k]  (bf16, k contiguous).
// K' is pre-scaled by KEXC. grid(x=64 bh, y=16 ktile) -> same-bh on same XCD.
// Single barrier/iter; 128-q chunks double-buffered via glds.
// ---------------------------------------------------------------------------
__global__ __launch_bounds__(256) void cs_vt(
    const unsigned short* __restrict__ Qb, const unsigned short* __restrict__ Kb,
    unsigned short* __restrict__ Vt)
{
  const int S = 1024, E = 1024;
  __shared__ __align__(16) unsigned short Ks[2][64 * 32];       // [dhalf]
  __shared__ __align__(16) unsigned short Qs[2][2][128 * 32];   // [buf][dhalf]
  __shared__ __align__(16) unsigned short T[64 * 72];
  __shared__ float Ls[64];
  const int bh = blockIdx.x, b = bh >> 4, h = bh & 15;
  const int k0 = blockIdx.y * 64;
  const int tid = threadIdx.x, wave = tid >> 6, lane = tid & 63;
  const int l15 = lane & 15, l4 = lane >> 4;
  const size_t rowBase = (size_t)b * S;
  const int srow = tid >> 2, scol = (tid & 3) * 8;

  glds16(&Kb[(rowBase + k0 + srow) * E + h * 64 + scol],      &Ks[0][tid * 8]);
  glds16(&Kb[(rowBase + k0 + srow) * E + h * 64 + 32 + scol], &Ks[1][tid * 8]);
  #pragma unroll
  for (int ds = 0; ds < 2; ++ds) {
    glds16(&Qb[(rowBase + srow) * E + h * 64 + ds * 32 + scol],      &Qs[0][ds][tid * 8]);
    glds16(&Qb[(rowBase + 64 + srow) * E + h * 64 + ds * 32 + scol], &Qs[0][ds][(tid + 256) * 8]);
  }

  float Lacc[4] = {};
  for (int it = 0; it < 8; ++it) {
    const int cur = it & 1;
    __syncthreads();             // vmcnt drain: Ks + Qs[cur] staged; old reads done
    if (it < 7) {
      const int q1 = (it + 1) * 128;
      #pragma unroll
      for (int ds = 0; ds < 2; ++ds) {
        glds16(&Qb[(rowBase + q1 + srow) * E + h * 64 + ds * 32 + scol],
               &Qs[1 - cur][ds][tid * 8]);
        glds16(&Qb[(rowBase + q1 + 64 + srow) * E + h * 64 + ds * 32 + scol],
               &Qs[1 - cur][ds][(tid + 256) * 8]);
      }
    }
    f32x4 accs[8] = {};
    #pragma unroll
    for (int ds = 0; ds < 2; ++ds) {
      bf16x8 af = *(const bf16x8*)&Ks[ds][(wave * 16 + l15) * 32 + l4 * 8];
      #pragma unroll
      for (int nj = 0; nj < 8; ++nj) {
        bf16x8 bv = *(const bf16x8*)&Qs[cur][ds][(nj * 16 + l15) * 32 + l4 * 8];
        accs[nj] = MFMA(af, bv, accs[nj]);
      }
    }
    #pragma unroll
    for (int nj = 0; nj < 8; ++nj)
      #pragma unroll
      for (int rr = 0; rr < 4; ++rr)
        Lacc[rr] += __builtin_amdgcn_exp2f(accs[nj][rr]);
  }
  #pragma unroll
  for (int off = 1; off < 16; off <<= 1)
    #pragma unroll
    for (int rr = 0; rr < 4; ++rr)
      Lacc[rr] += __shfl_xor(Lacc[rr], off);
  if (l15 == 0) {
    #pragma unroll
    for (int rr = 0; rr < 4; ++rr)
      Ls[wave * 16 + l4 * 4 + rr] = Lacc[rr];
  }
  __syncthreads();

  // Vt build: reload Q rows [k0,k0+64), scale by 1/L, transpose via LDS
  const int row = tid >> 2, d16 = (tid & 3) * 16;
  const float rl = 1.0f / Ls[row];
  const unsigned short* src = &Qb[(rowBase + k0 + row) * E + h * 64 + d16];
  us8 v0 = *(const us8*)src, v1 = *(const us8*)(src + 8);
  #pragma unroll
  for (int j = 0; j < 8; ++j) T[(d16 + j) * 72 + row]     = f2bf(bf2f(v0[j]) * rl);
  #pragma unroll
  for (int j = 0; j < 8; ++j) T[(d16 + 8 + j) * 72 + row] = f2bf(bf2f(v1[j]) * rl);
  __syncthreads();
  const int d = tid >> 2, kh = (tid & 3) * 16;
  unsigned short* dst = &Vt[((size_t)bh * 64 + d) * S + k0 + kh];
  *(us8*)dst       = *(const us8*)&T[d * 72 + kh];
  *(us8*)(dst + 8) = *(const us8*)&T[d * 72 + kh + 8];
}

// ---------------------------------------------------------------------------
// attn_out: per (bh, q-tile128): stream 16 k-tiles of 64.
// ONE barrier/iter: glds prefetch (double-buffered Ks/Vs) in flight across the
// whole iteration; Ps round-trip is wave-private (no barrier, lgkmcnt only).
// S arrives pre-scaled (K'=KEXC*K) -> exp2 is raw v_exp_f32.
// grid(x=64 bh, y=8 qtile) -> same-bh on same XCD.  LDS 64 KB.
// ---------------------------------------------------------------------------
__global__ __launch_bounds__(256) void attn_out(
    const unsigned short* __restrict__ Qb, const unsigned short* __restrict__ Kb,
    const unsigned short* __restrict__ VtH, unsigned short* __restrict__ O)
{
  const int S = 1024, E = 1024;
  __shared__ __align__(16) unsigned short Qs[2][128 * 32];      // [dhalf][q][d]
  __shared__ __align__(16) unsigned short Ks[2][2][64 * 32];    // [buf][dhalf][k][d]
  __shared__ __align__(16) unsigned short Vs[2][2][64 * 32];    // [buf][khalf][d][k]
  __shared__ __align__(16) unsigned short Ps[2][128 * 32];      // [khalf][q][k]
  const int bh = blockIdx.x, b = bh >> 4, h = bh & 15;
  const int q0 = blockIdx.y * 128;
  const int tid = threadIdx.x, wave = tid >> 6, lane = tid & 63;
  const int l15 = lane & 15, l4 = lane >> 4;
  const size_t rowBase = (size_t)b * S;
  const int srow = tid >> 2, scol = (tid & 3) * 8;
  const unsigned short* gK = &Kb[(rowBase + srow) * E + h * 64 + scol];
  const unsigned short* gV = &VtH[((size_t)bh * 64 + srow) * S + scol];

  #pragma unroll
  for (int ds = 0; ds < 2; ++ds) {
    glds16(&Qb[(rowBase + q0 + srow) * E + h * 64 + ds * 32 + scol],      &Qs[ds][tid * 8]);
    glds16(&Qb[(rowBase + q0 + 64 + srow) * E + h * 64 + ds * 32 + scol], &Qs[ds][(tid + 256) * 8]);
  }
  glds16(gK,      &Ks[0][0][tid * 8]);
  glds16(gK + 32, &Ks[0][1][tid * 8]);
  glds16(gV,      &Vs[0][0][tid * 8]);
  glds16(gV + 32, &Vs[0][1][tid * 8]);

  f32x4 acco[2][4] = {};
  for (int it = 0; it < 16; ++it) {
    const int cur = it & 1, k0 = it * 64;
    __syncthreads();   // vmcnt drain: Ks[cur],Vs[cur] (and Qs) staged; old buf reads done
    if (it < 15) {
      const size_t ko = (size_t)(k0 + 64);
      glds16(gK + ko * E,      &Ks[1 - cur][0][tid * 8]);
      glds16(gK + ko * E + 32, &Ks[1 - cur][1][tid * 8]);
      glds16(gV + ko,          &Vs[1 - cur][0][tid * 8]);
      glds16(gV + ko + 32,     &Vs[1 - cur][1][tid * 8]);
    }
    // S^T-GEMM: C[m=k][n=q] -> lane holds 4 contiguous k at fixed q
    f32x4 accs[4][2] = {};
    #pragma unroll
    for (int ds = 0; ds < 2; ++ds) {
      bf16x8 bq0 = *(const bf16x8*)&Qs[ds][(wave * 32 + l15) * 32 + l4 * 8];
      bf16x8 bq1 = *(const bf16x8*)&Qs[ds][(wave * 32 + 16 + l15) * 32 + l4 * 8];
      #pragma unroll
      for (int mi = 0; mi < 4; ++mi) {
        bf16x8 ak = *(const bf16x8*)&Ks[cur][ds][(mi * 16 + l15) * 32 + l4 * 8];
        accs[mi][0] = MFMA(ak, bq0, accs[mi][0]);
        accs[mi][1] = MFMA(ak, bq1, accs[mi][1]);
      }
    }
    // P = exp2(s) -> wave-private Ps rows [32*wave, 32*wave+32)
    #pragma unroll
    for (int mi = 0; mi < 4; ++mi) {
      #pragma unroll
      for (int nj = 0; nj < 2; ++nj) {
        const int q = wave * 32 + nj * 16 + l15;
        uint2 pk;
        pk.x = pack_bf2(__builtin_amdgcn_exp2f(accs[mi][nj][0]),
                        __builtin_amdgcn_exp2f(accs[mi][nj][1]));
        pk.y = pack_bf2(__builtin_amdgcn_exp2f(accs[mi][nj][2]),
                        __builtin_amdgcn_exp2f(accs[mi][nj][3]));
        *(uint2*)&Ps[mi >> 1][q * 32 + (mi & 1) * 16 + l4 * 4] = pk;
      }
    }
    // O-GEMM (same-wave Ps write->read ordered by lgkmcnt; no barrier)
    #pragma unroll
    for (int ks = 0; ks < 2; ++ks) {
      bf16x8 ap0 = *(const bf16x8*)&Ps[ks][(wave * 32 + l15) * 32 + l4 * 8];
      bf16x8 ap1 = *(const bf16x8*)&Ps[ks][(wave * 32 + 16 + l15) * 32 + l4 * 8];
      #pragma unroll
      for (int nj = 0; nj < 4; ++nj) {
        bf16x8 bv = *(const bf16x8*)&Vs[cur][ks][(nj * 16 + l15) * 32 + l4 * 8];
        acco[0][nj] = MFMA(ap0, bv, acco[0][nj]);
        acco[1][nj] = MFMA(ap1, bv, acco[1][nj]);
      }
    }
  }

  #pragma unroll
  for (int mi2 = 0; mi2 < 2; ++mi2)
    #pragma unroll
    for (int nj = 0; nj < 4; ++nj)
      #pragma unroll
      for (int rr = 0; rr < 4; ++rr)
        O[(rowBase + q0 + wave * 32 + mi2 * 16 + l4 * 4 + rr) * E + h * 64 + nj * 16 + l15] =
            f2bf(acco[mi2][nj][rr]);
}

// ---------------------------------------------------------------------------
// inputs: 0=X 1=W_q 2=b_q 3=W_k 4=b_k 5=W_v 6=b_v 7=W_o 8=b_o
// ws (bf16): Xbf[4M] Wqkt[2M] Wot[1M] Qb[4M] Kb[4M] Ob[4M] Vt[4M]  (~46 MB)
// ---------------------------------------------------------------------------
extern "C" void kernel_launch(void* const* d_in, const int* in_sizes, int n_in,
                              void* d_out, int out_size, void* d_ws, size_t ws_size,
                              hipStream_t stream)
{
  const float* X  = (const float*)d_in[0];
  const float* Wq = (const float*)d_in[1];
  const float* bq = (const float*)d_in[2];
  const float* Wk = (const float*)d_in[3];
  const float* bk = (const float*)d_in[4];
  const float* Wo = (const float*)d_in[7];
  const float* bo = (const float*)d_in[8];

  const int Mr = 4096, E = 1024;
  unsigned short* Xbf  = (unsigned short*)d_ws;
  unsigned short* Wqkt = Xbf  + (size_t)Mr * E;
  unsigned short* Wot  = Wqkt + (size_t)2 * E * E;
  unsigned short* Qb   = Wot  + (size_t)E * E;
  unsigned short* Kb   = Qb   + (size_t)Mr * E;
  unsigned short* Ob   = Kb   + (size_t)Mr * E;
  unsigned short* Vt   = Ob   + (size_t)Mr * E;

  prep<<<dim3(4864), dim3(256), 0, stream>>>(X, Wq, Wk, Wo, Xbf, Wqkt, Wot);

  // fused Q|K' projection (K' = KEXC-scaled)
  gemm_m97<1><<<dim3(16, 32), dim3(256), 0, stream>>>(
      Xbf, Wqkt, bq, bk, (void*)Qb, (void*)Kb, 2048, E, KEXC);

  cs_vt<<<dim3(64, 16), dim3(256), 0, stream>>>(Qb, Kb, Vt);
  attn_out<<<dim3(64, 8), dim3(256), 0, stream>>>(Qb, Kb, Vt, Ob);

  gemm_m97<0><<<dim3(8, 32), dim3(256), 0, stream>>>(
      Ob, Wot, bo, nullptr, d_out, nullptr, E, E, 1.0f);
}